// Round 1
// baseline (341.714 us; speedup 1.0000x reference)
//
#include <hip/hip_runtime.h>

#define BLOCK 256
#define CHUNK 8

__device__ __forceinline__ float leaky_(float x){ return x >= 0.f ? x : 0.01f*x; }

// ---------------- Kernel A: per-structure precompute ----------------
// ci_out[s*12 + 0..8]  = inv(cell[s]) row-major
// cc_out[s*32 + k]     = b2a[k] + sum_{j1,j2} cr[j1]*cr[j2]*w2a[k][9 + j1*9 + j2]
__global__ void prep_kernel(const float* __restrict__ cell,
                            const float* __restrict__ w2a,
                            const float* __restrict__ b2a,
                            float* __restrict__ ci_out,
                            float* __restrict__ cc_out,
                            int S)
{
    int gid = blockIdx.x * blockDim.x + threadIdx.x;
    int s = gid >> 5;
    if (s >= S) return;
    int k = gid & 31;

    float cr[9];
    #pragma unroll
    for (int j = 0; j < 9; j++) cr[j] = cell[s*9 + j];

    if (k == 0) {
        float a=cr[0],b=cr[1],c=cr[2],d=cr[3],e=cr[4],f=cr[5],g=cr[6],h=cr[7],i=cr[8];
        float A = e*i - f*h;
        float B = f*g - d*i;
        float C = d*h - e*g;
        float det = a*A + b*B + c*C;
        float r = 1.0f / det;
        float* o = ci_out + s*12;
        o[0] = A*r;         o[1] = (c*h - b*i)*r; o[2] = (b*f - c*e)*r;
        o[3] = B*r;         o[4] = (a*i - c*g)*r; o[5] = (c*d - a*f)*r;
        o[6] = C*r;         o[7] = (b*g - a*h)*r; o[8] = (a*e - b*d)*r;
    }

    float acc = b2a[k];
    const float* wr = w2a + k*90 + 9;
    #pragma unroll
    for (int j1 = 0; j1 < 9; j1++) {
        float c1 = cr[j1];
        #pragma unroll
        for (int j2 = 0; j2 < 9; j2++)
            acc = fmaf(c1 * cr[j2], wr[j1*9 + j2], acc);
    }
    cc_out[s*32 + k] = acc;
}

// ---------------- Kernel B: per-atom MLP + segment sum ----------------
// LDS layout (floats):
//   [0,288)   w2a9T[j][k] = w2a[k*90+j]          (j<9, k<32)   float4 idx j*8+k4
//   [288,800) w2bT[k][m]  = w2b[m*32+k]          (k<32, m<16)  float4 idx 72+k*4+m4
//   [800,928) w2cT[m][p]  = w2c[p*16+m], pad p<8 (m<16)        float4 idx 200+m*2+p4
//   [928,944) b2b
//   [944,952) b2c (pad 8)
//   [952..]   w0(9) b0(3) w1(9) b1(3) w1n(9) b1n(3)
__device__ __forceinline__ void compute_h9(
    float px, float py, float pz, float ax, float ay, float az,
    const float* ci,
    const float* lw0, const float* lb0,
    const float* lw1, const float* lb1,
    const float* lw1n, const float* lb1n,
    float* h9)
{
    float f0 = fmaf(px, ci[0], fmaf(py, ci[3], pz*ci[6]));
    float f1 = fmaf(px, ci[1], fmaf(py, ci[4], pz*ci[7]));
    float f2 = fmaf(px, ci[2], fmaf(py, ci[5], pz*ci[8]));
    float t0 = f0 - floorf(f0) - 0.5f;
    float t1 = f1 - floorf(f1) - 0.5f;
    float t2 = f2 - floorf(f2) - 0.5f;

    h9[0] = ax; h9[1] = ay; h9[2] = az;

    #pragma unroll
    for (int r = 0; r < 3; r++) {
        float ap3 = leaky_(fmaf(ax, lw0[r*3+0], fmaf(ay, lw0[r*3+1], fmaf(az, lw0[r*3+2], lb0[r]))));
        float d1  = fmaf(t0, lw1[r*3+0], fmaf(t1, lw1[r*3+1], fmaf(t2, lw1[r*3+2], lb1[r])));
        float d2  = lb1n[r] - (fmaf(t0, lw1n[r*3+0], fmaf(t1, lw1n[r*3+1], t2*lw1n[r*3+2])));
        h9[3+r] = fmaxf(d1, 0.f) * ap3;
        h9[6+r] = fmaxf(d2, 0.f) * ap3;
    }
}

__global__ __launch_bounds__(BLOCK)
void main_kernel(const float* __restrict__ atom_prop,
                 const float* __restrict__ pos,
                 const int*   __restrict__ batch,
                 const float* __restrict__ w0,  const float* __restrict__ b0,
                 const float* __restrict__ w1,  const float* __restrict__ b1,
                 const float* __restrict__ w1n, const float* __restrict__ b1n,
                 const float* __restrict__ w2a,
                 const float* __restrict__ w2b, const float* __restrict__ b2b,
                 const float* __restrict__ w2c, const float* __restrict__ b2c,
                 const float* __restrict__ ci_ws,
                 const float* __restrict__ cc_ws,
                 float* __restrict__ out,
                 int N)
{
    __shared__ float lds[992];
    int tid = threadIdx.x;
    for (int t = tid; t < 288; t += BLOCK) { int j = t >> 5, k = t & 31; lds[t] = w2a[k*90 + j]; }
    for (int t = tid; t < 512; t += BLOCK) { int k = t >> 4, m = t & 15; lds[288 + t] = w2b[m*32 + k]; }
    if (tid < 128) { int m = tid >> 3, p = tid & 7; lds[800 + tid] = (p < 6) ? w2c[p*16 + m] : 0.f; }
    if (tid < 16) lds[928 + tid] = b2b[tid];
    if (tid < 8)  lds[944 + tid] = (tid < 6) ? b2c[tid] : 0.f;
    if (tid < 9)  lds[952 + tid] = w0[tid];
    if (tid < 3)  lds[961 + tid] = b0[tid];
    if (tid < 9)  lds[964 + tid] = w1[tid];
    if (tid < 3)  lds[973 + tid] = b1[tid];
    if (tid < 9)  lds[976 + tid] = w1n[tid];
    if (tid < 3)  lds[985 + tid] = b1n[tid];
    __syncthreads();

    const float4* lds4 = (const float4*)lds;
    const float* lw0  = lds + 952; const float* lb0  = lds + 961;
    const float* lw1  = lds + 964; const float* lb1  = lds + 973;
    const float* lw1n = lds + 976; const float* lb1n = lds + 985;

    int base = (blockIdx.x * BLOCK + tid) * CHUNK;

    float acc[6] = {0.f,0.f,0.f,0.f,0.f,0.f};
    int cur_s = -1;
    float ci[9];
    float cc[32];

    for (int t = 0; t < CHUNK; t += 2) {
        int i = base + t;
        if (i >= N) break;
        bool hasB = (i + 1 < N);

        int sA, sB = -1;
        float pxA,pyA,pzA,pxB=0,pyB=0,pzB=0;
        float axA,ayA,azA,axB=0,ayB=0,azB=0;
        if (hasB) {
            int2 bb = *(const int2*)(batch + i);
            sA = bb.x; sB = bb.y;
            float2 p0 = *(const float2*)(pos + 3*i);
            float2 p1 = *(const float2*)(pos + 3*i + 2);
            float2 p2 = *(const float2*)(pos + 3*i + 4);
            pxA = p0.x; pyA = p0.y; pzA = p1.x; pxB = p1.y; pyB = p2.x; pzB = p2.y;
            float2 a0 = *(const float2*)(atom_prop + 3*i);
            float2 a1 = *(const float2*)(atom_prop + 3*i + 2);
            float2 a2 = *(const float2*)(atom_prop + 3*i + 4);
            axA = a0.x; ayA = a0.y; azA = a1.x; axB = a1.y; ayB = a2.x; azB = a2.y;
        } else {
            sA = batch[i];
            pxA = pos[3*i]; pyA = pos[3*i+1]; pzA = pos[3*i+2];
            axA = atom_prop[3*i]; ayA = atom_prop[3*i+1]; azA = atom_prop[3*i+2];
        }

        bool aSep = false;
        if (sA != cur_s) {
            if (cur_s >= 0) {
                #pragma unroll
                for (int p = 0; p < 6; p++) atomicAdd(out + cur_s*6 + p, acc[p]);
            }
            cur_s = sA;
            #pragma unroll
            for (int j = 0; j < 9; j++) ci[j] = ci_ws[sA*12 + j];
            const float4* cp = (const float4*)(cc_ws + sA*32);
            #pragma unroll
            for (int q = 0; q < 8; q++) {
                float4 v = cp[q];
                cc[4*q+0] = v.x; cc[4*q+1] = v.y; cc[4*q+2] = v.z; cc[4*q+3] = v.w;
            }
            #pragma unroll
            for (int p = 0; p < 6; p++) acc[p] = 0.f;
        }

        float h9A[9];
        compute_h9(pxA,pyA,pzA, axA,ayA,azA, ci, lw0,lb0,lw1,lb1,lw1n,lb1n, h9A);
        float uA[32];
        #pragma unroll
        for (int k = 0; k < 32; k++) uA[k] = cc[k];

        float h9B[9];
        float uB[32];
        if (hasB) {
            if (sB != cur_s) {
                #pragma unroll
                for (int p = 0; p < 6; p++) atomicAdd(out + cur_s*6 + p, acc[p]);
                cur_s = sB;
                #pragma unroll
                for (int j = 0; j < 9; j++) ci[j] = ci_ws[sB*12 + j];
                const float4* cp = (const float4*)(cc_ws + sB*32);
                #pragma unroll
                for (int q = 0; q < 8; q++) {
                    float4 v = cp[q];
                    cc[4*q+0] = v.x; cc[4*q+1] = v.y; cc[4*q+2] = v.z; cc[4*q+3] = v.w;
                }
                #pragma unroll
                for (int p = 0; p < 6; p++) acc[p] = 0.f;
                aSep = true;
            }
            compute_h9(pxB,pyB,pzB, axB,ayB,azB, ci, lw0,lb0,lw1,lb1,lw1n,lb1n, h9B);
            #pragma unroll
            for (int k = 0; k < 32; k++) uB[k] = cc[k];
        } else {
            #pragma unroll
            for (int j = 0; j < 9; j++) h9B[j] = 0.f;
            #pragma unroll
            for (int k = 0; k < 32; k++) uB[k] = 0.f;
        }

        // ---- L1: 9 -> 32 (weights shared across the pair) ----
        #pragma unroll
        for (int j = 0; j < 9; j++) {
            float ha = h9A[j], hb = h9B[j];
            #pragma unroll
            for (int k4 = 0; k4 < 8; k4++) {
                float4 w = lds4[j*8 + k4];
                uA[4*k4+0] = fmaf(ha, w.x, uA[4*k4+0]);
                uA[4*k4+1] = fmaf(ha, w.y, uA[4*k4+1]);
                uA[4*k4+2] = fmaf(ha, w.z, uA[4*k4+2]);
                uA[4*k4+3] = fmaf(ha, w.w, uA[4*k4+3]);
                uB[4*k4+0] = fmaf(hb, w.x, uB[4*k4+0]);
                uB[4*k4+1] = fmaf(hb, w.y, uB[4*k4+1]);
                uB[4*k4+2] = fmaf(hb, w.z, uB[4*k4+2]);
                uB[4*k4+3] = fmaf(hb, w.w, uB[4*k4+3]);
            }
        }
        #pragma unroll
        for (int k = 0; k < 32; k++) { uA[k] = fmaxf(uA[k], 0.f); uB[k] = fmaxf(uB[k], 0.f); }

        // ---- L2: 32 -> 16 ----
        float vA[16], vB[16];
        #pragma unroll
        for (int m = 0; m < 16; m++) { float b = lds[928 + m]; vA[m] = b; vB[m] = b; }
        #pragma unroll
        for (int k = 0; k < 32; k++) {
            float ua = uA[k], ub = uB[k];
            #pragma unroll
            for (int m4 = 0; m4 < 4; m4++) {
                float4 w = lds4[72 + k*4 + m4];
                vA[4*m4+0] = fmaf(ua, w.x, vA[4*m4+0]);
                vA[4*m4+1] = fmaf(ua, w.y, vA[4*m4+1]);
                vA[4*m4+2] = fmaf(ua, w.z, vA[4*m4+2]);
                vA[4*m4+3] = fmaf(ua, w.w, vA[4*m4+3]);
                vB[4*m4+0] = fmaf(ub, w.x, vB[4*m4+0]);
                vB[4*m4+1] = fmaf(ub, w.y, vB[4*m4+1]);
                vB[4*m4+2] = fmaf(ub, w.z, vB[4*m4+2]);
                vB[4*m4+3] = fmaf(ub, w.w, vB[4*m4+3]);
            }
        }
        #pragma unroll
        for (int m = 0; m < 16; m++) { vA[m] = leaky_(vA[m]); vB[m] = leaky_(vB[m]); }

        // ---- L3: 16 -> 6 (padded to 8) ----
        float oA[8], oB[8];
        #pragma unroll
        for (int p = 0; p < 8; p++) { float b = lds[944 + p]; oA[p] = b; oB[p] = b; }
        #pragma unroll
        for (int m = 0; m < 16; m++) {
            float va = vA[m], vb = vB[m];
            #pragma unroll
            for (int p4 = 0; p4 < 2; p4++) {
                float4 w = lds4[200 + m*2 + p4];
                oA[4*p4+0] = fmaf(va, w.x, oA[4*p4+0]);
                oA[4*p4+1] = fmaf(va, w.y, oA[4*p4+1]);
                oA[4*p4+2] = fmaf(va, w.z, oA[4*p4+2]);
                oA[4*p4+3] = fmaf(va, w.w, oA[4*p4+3]);
                oB[4*p4+0] = fmaf(vb, w.x, oB[4*p4+0]);
                oB[4*p4+1] = fmaf(vb, w.y, oB[4*p4+1]);
                oB[4*p4+2] = fmaf(vb, w.z, oB[4*p4+2]);
                oB[4*p4+3] = fmaf(vb, w.w, oB[4*p4+3]);
            }
        }

        if (aSep) {
            #pragma unroll
            for (int p = 0; p < 6; p++) atomicAdd(out + sA*6 + p, oA[p]);
        } else {
            #pragma unroll
            for (int p = 0; p < 6; p++) acc[p] += oA[p];
        }
        if (hasB) {
            #pragma unroll
            for (int p = 0; p < 6; p++) acc[p] += oB[p];
        }
    }

    if (cur_s >= 0) {
        #pragma unroll
        for (int p = 0; p < 6; p++) atomicAdd(out + cur_s*6 + p, acc[p]);
    }
}

extern "C" void kernel_launch(void* const* d_in, const int* in_sizes, int n_in,
                              void* d_out, int out_size, void* d_ws, size_t ws_size,
                              hipStream_t stream)
{
    const float* atom_prop = (const float*)d_in[0];
    const float* pos       = (const float*)d_in[1];
    const float* cell      = (const float*)d_in[2];
    const int*   batch     = (const int*)  d_in[3];
    const float* w0  = (const float*)d_in[4];
    const float* b0  = (const float*)d_in[5];
    const float* w1  = (const float*)d_in[6];
    const float* b1  = (const float*)d_in[7];
    const float* w1n = (const float*)d_in[8];
    const float* b1n = (const float*)d_in[9];
    const float* w2a = (const float*)d_in[10];
    const float* b2a = (const float*)d_in[11];
    const float* w2b = (const float*)d_in[12];
    const float* b2b = (const float*)d_in[13];
    const float* w2c = (const float*)d_in[14];
    const float* b2c = (const float*)d_in[15];

    int N = in_sizes[3];          // batch has one entry per atom
    int S = in_sizes[2] / 9;      // cell is [S,3,3]

    float* out   = (float*)d_out;
    float* ci_ws = (float*)d_ws;              // [S,12]
    float* cc_ws = (float*)d_ws + (size_t)S*12; // [S,32]

    hipMemsetAsync(d_out, 0, (size_t)out_size * sizeof(float), stream);

    int prep_threads = S * 32;
    prep_kernel<<<(prep_threads + 255)/256, 256, 0, stream>>>(cell, w2a, b2a, ci_ws, cc_ws, S);

    int total_threads = (N + CHUNK - 1) / CHUNK;
    int grid = (total_threads + BLOCK - 1) / BLOCK;
    main_kernel<<<grid, BLOCK, 0, stream>>>(atom_prop, pos, batch,
                                            w0, b0, w1, b1, w1n, b1n,
                                            w2a, w2b, b2b, w2c, b2c,
                                            ci_ws, cc_ws, out, N);
}